// Round 8
// baseline (478.756 us; speedup 1.0000x reference)
//
#include <hip/hip_runtime.h>

// ---------------------------------------------------------------------------
// KAN 2-layer forward, round 15 = r14 with the prologue swizzle-key bugfix.
// r14 theory (unmeasured due to the bug): r7..r13's six structures all hit
// ~260us L1 because each streamed 2.68 GB of B per dispatch (64-row
// m-blocks x full W1 slice) at ~10.3 TB/s = the L3/Infinity-Cache ceiling.
// r15: BM=256 -> B-traffic /4 (671 MB); XCD quadrant pinning (bid&3 =
// (nz,kz) quadrant, 2.62MB W-slice < 4MB XCD-L2, bid&7 = XCD) -> B becomes
// L2-hits. 8 waves (2m x 4n), acc[4][2] f32x16 = 128 AGPR, 1 block/CU.
// B single-buffered in regs (act VALU covers L2 latency). A staged in LDS
// 8-feature supersteps (dbuf 2x32KB).
// BUG FIXED vs r14: prologue A-stage used swizzle key r5&7 (=t&7) instead of
// the staged ROW's key sr&7 (=(t>>1)&7) -> superstep 0 fragments garbage,
// absmax 1.8. Loop staging + reads were already consistent.
// ---------------------------------------------------------------------------

typedef short s16x8 __attribute__((ext_vector_type(8)));  // 8 bf16 = 4 VGPRs
typedef float f32x4 __attribute__((ext_vector_type(4)));
typedef float f32x16 __attribute__((ext_vector_type(16)));

__device__ __forceinline__ unsigned pk2(float lo, float hi) {
  unsigned a = __float_as_uint(lo), b = __float_as_uint(hi);
  a = a + 0x7fffu + ((a >> 16) & 1u);
  b = b + 0x7fffu + ((b >> 16) & 1u);
  return __builtin_amdgcn_perm(b, a, 0x07060302u);  // {b.hi16, a.hi16}
}

__device__ __forceinline__ unsigned short f2bf(float f) {
  unsigned u = __float_as_uint(f);
  unsigned r = u + 0x7fffu + ((u >> 16) & 1u);
  return (unsigned short)(r >> 16);
}

// silu + 6 cubic B-spline bases (uniform extended grid, u = 1.5x+4.5, knots
// u=0..9; recursion ref-verified r1..r13). Packed bf16x8 [silu,b3'_0..5,0]
// where b3' = 6*b3 (the 1/6 is folded into the weights in prep_w).
__device__ __forceinline__ s16x8 kan_act8(float x) {
  float e = __expf(-x);
  float s = x * __builtin_amdgcn_rcpf(1.0f + e);
  float u = fmaf(x, 1.5f, 4.5f);
  float d[10];
#pragma unroll
  for (int j = 0; j < 10; ++j) d[j] = u - (float)j;
  float b1[8];
#pragma unroll
  for (int j = 0; j < 8; ++j) b1[j] = fmaxf(0.0f, 1.0f - fabsf(d[j + 1]));
  float B2[7];
#pragma unroll
  for (int j = 0; j < 7; ++j) B2[j] = d[j] * b1[j] - d[j + 3] * b1[j + 1];
  float b3[6];
#pragma unroll
  for (int j = 0; j < 6; ++j)
    b3[j] = d[j] * B2[j] - d[j + 4] * B2[j + 1];   // 6x the basis; W has /6
  union { uint4 u4; s16x8 v; } r;
  r.u4.x = pk2(s, b3[0]);
  r.u4.y = pk2(b3[1], b3[2]);
  r.u4.z = pk2(b3[3], b3[4]);
  r.u4.w = pk2(b3[5], 0.0f);
  return r.v;
}

// Transposed packed weights: WT[f][col] = s16x8 {base_w, spline_w*sc/6 x6, 0}.
// Chunk index = f*Ncols + col. Cols >= Nvalid zeroed (padding).
__global__ __launch_bounds__(256) void prep_w(
    const float* __restrict__ base_w, const float* __restrict__ spline_w,
    const float* __restrict__ scaler, short* __restrict__ WT,
    int F, int Ncols, int Nvalid) {
  int i = blockIdx.x * 256 + threadIdx.x;  // feature (coalesced reads)
  int n = blockIdx.y;                      // output col
  if (i >= F) return;
  s16x8 v;
#pragma unroll
  for (int k = 0; k < 8; ++k) v[k] = 0;
  if (n < Nvalid) {
    int idx = n * F + i;
    float sc = scaler[idx] * (1.0f / 6.0f);
    v[0] = (short)f2bf(base_w[idx]);
#pragma unroll
    for (int k = 0; k < 6; ++k) v[1 + k] = (short)f2bf(spline_w[idx * 6 + k] * sc);
  }
  *(s16x8*)&WT[((size_t)i * Ncols + n) * 8] = v;
}

// BM=256 superstep fused-act GEMM. 512 threads = 8 waves (2m x 4n): wave
// (wm,wn) owns rows [wm*128,+128) (4 m-tiles), cols [c0+wn*64,+64) (2
// n-tiles); acc[4][2] f32x16. Superstep = 8 features: 512 threads each act
// a float4 (row t>>1, feats (t&1)*4..+3) -> As dbuf (2 x 32KB, row stride
// 128B, feat-slot ^= row&7). B single-buffered in regs from f-major WT.
// XSWZ decode: bid&1 = n-half, (bid>>1)&1 = K-part (both on bid&7 = XCD ->
// 2.62MB W quadrant L2-pinned), m = bid >> 2.
template <int Ncols, bool XSWZ>
__global__ __launch_bounds__(512, 2) void kan_gemm(
    const float* __restrict__ X, const short* __restrict__ WT,
    float* __restrict__ Cp, int F, int span, long long pstride, int kparts) {
  __shared__ __align__(16) short As[2][256 * 64];  // 2 x 32KB

  const int t    = threadIdx.x;
  const int lane = t & 63;
  const int w    = t >> 6;
  const int wm   = w >> 2;
  const int wn   = w & 3;
  const int r5   = lane & 31;
  const int hi   = lane >> 5;
  const int s3   = r5 & 7;   // read-side swizzle key: row&7 (rows differ from
                             // r5 by multiples of 8, so r5&7 == row&7)

  int mblk, colbase, f0, pz;
  if (XSWZ) {
    const int bid = blockIdx.x;
    const int nz  = bid & 1;
    pz      = (kparts == 2) ? ((bid >> 1) & 1) : 0;
    mblk    = bid >> ((kparts == 2) ? 2 : 1);
    colbase = nz * (Ncols / 2);
    f0      = pz * span;
  } else {
    mblk    = blockIdx.x;
    colbase = 0;
    pz      = blockIdx.z;
    f0      = pz * span;
  }
  const int m0 = mblk * 256;
  const int c0 = colbase + wn * 64;

  // act staging: thread -> row t>>1, features fg..fg+3 (float4 from X)
  const int sr = t >> 1, fg = (t & 1) * 4;
  const int sk = sr & 7;  // WRITE-side swizzle key: the staged row's &7
  const float* xrow = X + (size_t)(m0 + sr) * F + f0 + fg;
  const int awb = sr * 64;

  // B: lane -> col c0 + nt*32 + r5, feature ss*8 + kq*2 + hi
  const s16x8* wB = (const s16x8*)WT + (size_t)(f0 + hi) * Ncols + c0 + r5;

  f32x16 acc[4][2] = {};
  const int nss = span >> 3;

  // prologue: act+stage ss=0 (FIX: key sk, not s3); xA = x for ss=1
  {
    f32x4 xv = *(const f32x4*)xrow;
#pragma unroll
    for (int j = 0; j < 4; ++j) {
      s16x8 a = kan_act8(xv[j]);
      *(s16x8*)&As[0][awb + (((fg + j) ^ sk) * 8)] = a;
    }
  }
  f32x4 xA = *(const f32x4*)(xrow + 8);
  __syncthreads();

  for (int ss = 0; ss < nss; ++ss) {
    const int cb = ss & 1, nb = cb ^ 1;
    const bool more = (ss + 1 < nss);

    // B loads for this superstep (8 x dwordx4; L2-resident quadrant)
    s16x8 bc[4][2];
#pragma unroll
    for (int kq = 0; kq < 4; ++kq)
#pragma unroll
      for (int nt = 0; nt < 2; ++nt)
        bc[kq][nt] = wB[(size_t)(ss * 8 + kq * 2) * Ncols + nt * 32];

    // x prefetch for ss+2 (clamped)
    const int pf = (ss + 2 < nss) ? ss + 2 : nss - 1;
    f32x4 xB = *(const f32x4*)(xrow + (size_t)pf * 8);

    // act for ss+1 (VALU ~1400 cyc: covers the B L2 latency)
    if (more) {
#pragma unroll
      for (int j = 0; j < 4; ++j) {
        s16x8 a = kan_act8(xA[j]);
        *(s16x8*)&As[nb][awb + (((fg + j) ^ sk) * 8)] = a;
      }
    }

    // MFMA over 4 k-slots
    const short* Ac = As[cb];
#pragma unroll
    for (int kq = 0; kq < 4; ++kq) {
      const int co = ((kq * 2 + hi) ^ s3) * 8;
      s16x8 am[4];
#pragma unroll
      for (int mt = 0; mt < 4; ++mt)
        am[mt] = *(const s16x8*)(Ac + (wm * 128 + mt * 32 + r5) * 64 + co);
#pragma unroll
      for (int mt = 0; mt < 4; ++mt)
#pragma unroll
        for (int nt = 0; nt < 2; ++nt)
          acc[mt][nt] = __builtin_amdgcn_mfma_f32_32x32x16_bf16(
              am[mt], bc[kq][nt], acc[mt][nt], 0, 0, 0);
    }

    __syncthreads();
    xA = xB;
  }

  // C/D layout (32x32): col = lane&31, row = (reg&3)+8*(reg>>2)+4*hi
  // (verified r10..r13). 32 consecutive cols per store -> 128B segments.
  float* cpt = Cp + (size_t)pz * (size_t)pstride;
#pragma unroll
  for (int mt = 0; mt < 4; ++mt) {
#pragma unroll
    for (int nt = 0; nt < 2; ++nt) {
      const int col = c0 + nt * 32 + r5;
#pragma unroll
      for (int reg = 0; reg < 16; ++reg) {
        const int row = m0 + wm * 128 + mt * 32 + (reg & 3) + 8 * (reg >> 2) + 4 * hi;
        cpt[(size_t)row * Ncols + col] = acc[mt][nt][reg];
      }
    }
  }
}

// h = LayerNorm(p0 + p1) over D=512, one wave per row.
__global__ __launch_bounds__(256) void ln_reduce(
    const float* __restrict__ p0, const float* __restrict__ p1,
    float* __restrict__ h, const float* __restrict__ gamma,
    const float* __restrict__ beta, int nparts) {
  int lane = threadIdx.x & 63;
  int wv   = threadIdx.x >> 6;
  int row  = blockIdx.x * 4 + wv;
  size_t base = (size_t)row * 512 + lane * 8;
  f32x4 v0 = *(const f32x4*)(p0 + base);
  f32x4 v1 = *(const f32x4*)(p0 + base + 4);
  if (nparts == 2) {
    f32x4 u0 = *(const f32x4*)(p1 + base);
    f32x4 u1 = *(const f32x4*)(p1 + base + 4);
#pragma unroll
    for (int k = 0; k < 4; ++k) { v0[k] += u0[k]; v1[k] += u1[k]; }
  }
  float s = 0.f, s2 = 0.f;
#pragma unroll
  for (int k = 0; k < 4; ++k) { s += v0[k] + v1[k]; s2 += v0[k]*v0[k] + v1[k]*v1[k]; }
#pragma unroll
  for (int m = 32; m >= 1; m >>= 1) {
    s  += __shfl_xor(s,  m, 64);
    s2 += __shfl_xor(s2, m, 64);
  }
  float mean = s * (1.0f / 512.0f);
  float var  = s2 * (1.0f / 512.0f) - mean * mean;
  float rstd = rsqrtf(var + 1e-5f);
  const f32x4 g0 = *(const f32x4*)(gamma + lane * 8);
  const f32x4 g1 = *(const f32x4*)(gamma + lane * 8 + 4);
  const f32x4 be0 = *(const f32x4*)(beta + lane * 8);
  const f32x4 be1 = *(const f32x4*)(beta + lane * 8 + 4);
#pragma unroll
  for (int k = 0; k < 4; ++k) {
    v0[k] = (v0[k] - mean) * rstd * g0[k] + be0[k];
    v1[k] = (v1[k] - mean) * rstd * g1[k] + be1[k];
  }
  *(f32x4*)(h + base) = v0;
  *(f32x4*)(h + base + 4) = v1;
}

// out[b][c<229] = sum_z p[z*pstride + b*256 + c] from 256-wide partials.
__global__ __launch_bounds__(256) void out_reduce(
    const float* __restrict__ p, float* __restrict__ out,
    int nparts, long long pstride) {
  int idx = blockIdx.x * 256 + threadIdx.x;
  int row = idx >> 8;
  int c   = idx & 255;
  float v = 0.0f;
  for (int z = 0; z < nparts; ++z) v += p[(size_t)z * pstride + idx];
  if (c < 229) out[(size_t)row * 229 + c] = v;
}

extern "C" void kernel_launch(void* const* d_in, const int* in_sizes, int n_in,
                              void* d_out, int out_size, void* d_ws, size_t ws_size,
                              hipStream_t stream) {
  const float* x         = (const float*)d_in[0];
  const float* base_w1   = (const float*)d_in[1];
  const float* spline_w1 = (const float*)d_in[2];
  const float* scaler1   = (const float*)d_in[3];
  const float* ln_gamma  = (const float*)d_in[4];
  const float* ln_beta   = (const float*)d_in[5];
  const float* base_w2   = (const float*)d_in[6];
  const float* spline_w2 = (const float*)d_in[7];
  const float* scaler2   = (const float*)d_in[8];
  float* out = (float*)d_out;

  const int B = 16384, D_IN = 1280, D_HID = 512, D_OUT = 229;

  // ws layout: W1pT | W2pT | h | p0 | p1   (~113 MB with parts=2)
  const size_t szW1 = (size_t)D_IN * D_HID * 8 * 2;   // 10,485,760 (f-major)
  const size_t szW2 = (size_t)D_HID * 256 * 8 * 2;    //  2,097,152
  const size_t szH  = (size_t)B * D_HID * 4;          // 33,554,432
  const size_t szP  = (size_t)B * 512 * 4;            // 33,554,432 slot
  char* ws = (char*)d_ws;
  short* W1p = (short*)ws;
  short* W2p = (short*)(ws + szW1);
  float* h   = (float*)(ws + szW1 + szW2);
  float* p0  = (float*)(ws + szW1 + szW2 + szH);

  const int parts = (ws_size >= szW1 + szW2 + szH + 2 * szP) ? 2 : 1;
  const long long pstride1 = (long long)(szP / 4);      // 8388608 elements
  float* p1 = p0 + pstride1;

  const int kp1 = parts;                 // L1 split-K
  const int kp2 = (parts == 2) ? 4 : 2;  // L2 split-K
  const long long pstride2 = (long long)B * 256;        // 4194304 elements

  prep_w<<<dim3(D_IN / 256, D_HID), 256, 0, stream>>>(
      base_w1, spline_w1, scaler1, W1p, D_IN, D_HID, D_HID);
  prep_w<<<dim3(D_HID / 256, 256), 256, 0, stream>>>(
      base_w2, spline_w2, scaler2, W2p, D_HID, 256, D_OUT);

  // layer 1: (16384 x 1280) -> split-K+n-split partials (16384 x 512):
  // 64 m-blocks x 2 n-halves x kp1 K-parts, XCD-quadrant-pinned decode.
  kan_gemm<512, true><<<dim3(64 * 2 * kp1, 1, 1), 512, 0, stream>>>(
      x, W1p, p0, D_IN, D_IN / kp1, pstride1, kp1);

  ln_reduce<<<dim3(B / 4), 256, 0, stream>>>(p0, p1, h, ln_gamma, ln_beta, parts);

  // layer 2: (16384 x 512) -> split-K partials (16384 x 256) x kp2
  kan_gemm<256, false><<<dim3(64, 1, kp2), 512, 0, stream>>>(
      h, W2p, p0, D_HID, D_HID / kp2, pstride2, kp2);

  out_reduce<<<dim3(B * 256 / 256), 256, 0, stream>>>(p0, out, kp2, pstride2);
}